// Round 13
// baseline (236.374 us; speedup 1.0000x reference)
//
#include <hip/hip_runtime.h>
#include <stdint.h>

#define T_TOTAL 1096
#define WARMUP  365
#define NB      16384
#define T_OUT   (T_TOTAL - WARMUP)   // 731
#define U       8                    // steps per group
#define NG      (T_TOTAL / U)        // 137 real groups (+1 dummy)
#define G_STORE 46                   // first group whose prev-group outputs get stored
#define RS      131072u              // input row stride bytes = NB*2*4
#define ORS     65536u               // output row stride bytes = NB*4
#define EOFF    47906816u            // et plane byte offset = T_OUT*NB*4

#define KEEP(x) asm volatile("" : "+v"(x))

typedef float f2 __attribute__((ext_vector_type(2)));
typedef float f4 __attribute__((ext_vector_type(4)));
typedef int   i2 __attribute__((ext_vector_type(2)));

typedef __attribute__((address_space(3))) char      lds_char;
typedef __attribute__((address_space(3))) uint32_t  lds_u32;
typedef const __attribute__((address_space(1))) uint32_t glb_u32;
typedef const __attribute__((address_space(3))) f4       lds_f4;

#define VMAX(a, b) __builtin_elementwise_max(a, b)
#define VMIN(a, b) __builtin_elementwise_min(a, b)
#define VFMA(a, b, c) __builtin_elementwise_fma(a, b, c)

// Stores only READ registers -> safe as inline asm (unlike loads, whose
// in-flight destination regs the allocator may copy/spill before the wait —
// the R12 corruption). 32-bit voffset + SGPR base: no VCC carry chains.
#define GSTORE2(off, val) \
    asm volatile("global_store_dwordx2 %0, %1, %2" \
                 :: "v"(off), "v"(val), "s"(out))

// One group of U=8 steps, two basins per lane, packed f32 (VOP3P).
// Input path: global_load_lds (no VGPR dest -> no scoreboard hazard),
// double-buffered LDS, filled one full group ahead; vmcnt(0) at group top
// drains only group-old traffic (no stall).
#define GROUP(g, CUROFF, NXTOFF, DO_ET) do {                                  \
        asm volatile("s_waitcnt vmcnt(0)" ::: "memory");                      \
        __builtin_amdgcn_sched_barrier(0);                                    \
        {   /* async-fill other buffer with group g+1 (dummy: reload t=0) */  \
            const size_t t0n = ((g) + 1 < NG) ? (size_t)((g) + 1) * (8u * RS) : 0; \
            _Pragma("unroll")                                                 \
            for (int k = 0; k < U; ++k)                                       \
                __builtin_amdgcn_global_load_lds(                             \
                    (glb_u32*)(pe_base + t0n + (size_t)k * RS),               \
                    (lds_u32*)((lds_char*)smem + (NXTOFF) + k * 1024),        \
                    16, 0, 0);                                                \
        }                                                                     \
        if ((g) >= G_STORE) {  /* store outputs of group g-1 */               \
            const int tbP = ((g) - 1) * U - WARMUP;                           \
            _Pragma("unroll")                                                 \
            for (int r = 0; r < U; ++r) {                                     \
                int to = tbP + r; if (to < 0) to = 0;   /* scalar clamp */    \
                const uint32_t voq = vb8 + (uint32_t)to * ORS;                \
                GSTORE2(voq, oq[r]);                                          \
                GSTORE2(voq + EOFF, oe[r]);                                   \
            }                                                                 \
        }                                                                     \
        asm volatile("" ::: "memory");                                        \
        /* stage current buffer LDS -> regs (compiler-managed lgkmcnt) */     \
        f4 s[U];                                                              \
        _Pragma("unroll")                                                     \
        for (int r = 0; r < U; ++r)                                           \
            s[r] = *(lds_f4*)((lds_char*)smem + (CUROFF) + r * 1024 + lane16);\
        _Pragma("unroll")                                                     \
        for (int r = 0; r < U; ++r) KEEP(s[r]);                               \
        _Pragma("unroll")                                                     \
        for (int r = 0; r < U; ++r) {                                         \
            const f2 p  = s[r].xz;   /* inputs >=0: clip is identity */       \
            const f2 e  = s[r].yw;                                            \
            const f2 ep = kc * e;                                             \
            const f2 pd = p - ep;                                             \
            const f2 pe = VMAX(pd, z2);                                       \
            const f2 d0 = VMAX(-pd, z2);                                      \
            if (DO_ET) oe[r] = VMIN(ep, p + (xp + xf));                       \
            const f2 g0 = VMAX(d0 - xf, z2);                                  \
            xf = VMAX(xf - d0, z2);                                           \
            xp = VMAX(xp - g0, z2);                                           \
            const f2 t1 = k1 * VMIN(x2, w1 - xp);                             \
            xp += t1;                                                         \
            x2 = VMAX(x2 - t1, z2);                                           \
            const f2 t2 = VMAX(VFMA(cxs, xs, -(cxp * xp)), z2);               \
            xp += t2;                                                         \
            xs = VMAX(xs - t2, z2);                                           \
            const f2 xppe = xp + pe;                                          \
            xf = xf + VMAX(xppe - w1, z2);                                    \
            xp = VMIN(w1, xppe);                                              \
            const f2 f1v = a0 * xf;                                           \
            const f2 s1v = VFMA(xf, a1, nh1a1);                               \
            const f2 s2v = VFMA(xf, a2, nh2a2);                               \
            /* a2>0: h2-select == fmax(s2v,0) */                              \
            const f2 rsv = VMAX(s2v, z2) + ((xf > hm) ? s1v : z2);            \
            x2 = x2 + f1v;                                                    \
            xf = VMAX(xf - (rsv + f1v), z2);                                  \
            const f2 f2v = b0 * x2;                                           \
            const f2 riv = VMAX(VFMA(x2, b1, nh3b1), z2);                     \
            x2 = VMAX(x2 - (f2v + riv), z2);                                  \
            x3 = x3 + f2v;                                                    \
            const f2 f3v = c0p * x3;                                          \
            const f2 rgv = VMAX(VFMA(x3, c1p, nh4c1), z2);                    \
            x3 = VMAX(x3 - (f3v + rgv), z2);                                  \
            x4 = x4 + f3v;                                                    \
            const f2 rgd = d1 * x4;                                           \
            x4 = VMAX(x4 - rgd, z2);                                          \
            const i2 c5 = x5 >= h;                                            \
            const f2 ii = (rsv + riv) + (rgv + rgd);                          \
            const f2 q1B = VMAX(VFMA(c5 ? gAdB : gBdB, qs,                    \
                                     VFMA(ii, dB, c5 ? ccAdB : z2)), z2);     \
            const f2 q1A = VMAX(VFMA(c5 ? gAdA : gBdA, qs,                    \
                                     VFMA(ii, dA, c5 ? z2 : nccAdA)), z2);    \
            const i2 cb = q1B > he1;                                          \
            const f2 q1 = cb ? q1A : q1B;                                     \
            x5 = cb ? VFMA(kkA, q1A, ccA) : (kkB * q1B);                      \
            qs = q1;                                                          \
            oq[r] = q1;                                                       \
        }                                                                     \
    } while (0)

#define KEEP_CONSTS() do {                                                    \
        KEEP(kc);  KEEP(w1);  KEEP(k1);  KEEP(cxs); KEEP(cxp);                \
        KEEP(a0);  KEEP(b0);  KEEP(c0p); KEEP(hm);                            \
        KEEP(a1);  KEEP(a2);  KEEP(b1);  KEEP(c1p); KEEP(d1);                 \
        KEEP(h);   KEEP(he1);                                                 \
        KEEP(kkA); KEEP(kkB); KEEP(ccA); KEEP(dA);  KEEP(dB);                 \
        KEEP(gAdA); KEEP(gBdA); KEEP(gAdB); KEEP(gBdB);                       \
        KEEP(ccAdB); KEEP(nccAdA);                                            \
        KEEP(nh1a1); KEEP(nh2a2); KEEP(nh3b1); KEEP(nh4c1);                   \
    } while (0)

// 8192 threads: each lane simulates 2 adjacent basins via packed f32.
// waves_per_eu(1,1): full VGPR budget (verified R10: no spills at 132+).
__global__ __attribute__((amdgpu_flat_work_group_size(64, 64)))
__attribute__((amdgpu_waves_per_eu(1, 1)))
void tank_kernel(
    const float* __restrict__ pe_in,   // [T, B, 2]
    const float* __restrict__ params,  // [B, 20]
    float* __restrict__ out)           // q [731,B] then et [731,B]
{
    const int lane = threadIdx.x;              // 0..63, one wave per block
    const int b    = blockIdx.x * 64 + lane;   // pair index: basins 2b, 2b+1

    __shared__ char smem[16384];               // 2 x 8KB double buffer

    const float* pp = params + (size_t)(2 * b) * 20;
    f2 pn[20];
#pragma unroll
    for (int i = 0; i < 20; ++i) pn[i] = (f2){ pp[i], pp[20 + i] };

    const f2 z2 = { 0.0f, 0.0f };

    f2 kc  = 0.5f  + pn[0]  * 1.0f;
    f2 w1  = 1.0f  + pn[1]  * 99.0f;
    f2 w2  = 1.0f  + pn[2]  * 99.0f;
    f2 k1  = 0.01f + pn[3]  * 0.99f;
    f2 k2  = 0.01f + pn[4]  * 0.99f;
    f2 a0  = 0.01f + pn[5]  * 0.99f;
    f2 b0  = 0.01f + pn[6]  * 0.99f;
    f2 c0p = 0.01f + pn[7]  * 0.99f;
    f2 h1  = pn[8]  * 90.0f;
    f2 h2  = pn[9]  * 100.0f;
    f2 a1  = 0.01f + pn[10] * 0.99f;
    f2 a2  = 0.01f + pn[11] * 0.99f;
    f2 h3  = pn[12] * 100.0f;
    f2 b1  = 0.01f + pn[13] * 0.99f;
    f2 h4  = pn[14] * 100.0f;
    f2 c1p = 0.01f + pn[15] * 0.99f;
    f2 d1  = 0.001f+ pn[16] * 0.999f;
    f2 e1  = 0.01f + pn[17] * 0.99f;
    f2 e2  = 0.01f + pn[18] * 0.99f;
    f2 h   = pn[19] * 100.0f;

    const float dt = 0.5f * (1.0f / 1000.0f);
    f2 invw = 1.0f / (w1 + w2);
    f2 cxs  = k2 * w1 * invw;
    f2 cxp  = k2 * w2 * invw;
    f2 kkA  = 1.0f / (e1 + e2);
    f2 kkB  = 1.0f / e1;
    f2 ccA  = e2 * h * kkA;
    f2 dA   = 1.0f / (kkA + dt);
    f2 dB   = 1.0f / (kkB + dt);
    f2 gAdA = (kkA - dt) * dA, gBdA = (kkB - dt) * dA;
    f2 gAdB = (kkA - dt) * dB, gBdB = (kkB - dt) * dB;
    f2 nh1a1 = -h1 * a1;
    f2 nh2a2 = -h2 * a2;
    f2 nh3b1 = -h3 * b1;
    f2 nh4c1 = -h4 * c1p;
    f2 hm    = VMIN(h1, h2);
    f2 he1   = h * e1;
    f2 ccAdB = ccA * dB;
    f2 nccAdA = -ccA * dA;

    f2 xf = {0.01f, 0.01f}, xp = xf, x2 = xf, xs = xf;
    f2 x3 = xf, x4 = xf, x5 = xf, qs = xf;

    // staging addressing: wave covers 128 basins = 1024B per time row
    const char* pe_base = (const char*)pe_in + (size_t)blockIdx.x * 1024
                        + (size_t)lane * 16;   // per-lane global src
    const uint32_t lane16 = (uint32_t)lane * 16;  // LDS read offset
    const uint32_t vb8    = (uint32_t)b * 8u;     // output pair byte offset

    f2 oq[U], oe[U];

    // prologue: fill buffer 0 with group 0 (t=0..7)
#pragma unroll
    for (int k = 0; k < U; ++k)
        __builtin_amdgcn_global_load_lds(
            (glb_u32*)(pe_base + (size_t)k * RS),
            (lds_u32*)((lds_char*)smem + k * 1024), 16, 0, 0);

    // Phase 1: pure-warmup groups 0..43 as 22 pairs (no et, no stores).
#pragma clang loop unroll(disable)
    for (int gp = 0; gp < 22; ++gp) {
        KEEP_CONSTS();
        const int g0i = 2 * gp;
        GROUP(g0i,     0,    8192, 0);
        GROUP(g0i + 1, 8192, 0,    0);
    }
    // groups 44 (no et) and 45 (t=360..367: et needed, outputs buffered;
    // stored at top of group 46 with scalar row clamp).
    KEEP_CONSTS();
    GROUP(44, 0,    8192, 0);
    GROUP(45, 8192, 0,    1);

    // Phase 2: output groups 46..137 as 46 pairs. Group 137 is a dummy:
    // computes discarded garbage from in-bounds t=0 data; its store slot
    // writes group 136's real outputs (rows 723..730).
#pragma clang loop unroll(disable)
    for (int gp = 0; gp < 46; ++gp) {
        KEEP_CONSTS();
        const int g0i = 46 + 2 * gp;
        GROUP(g0i,     0,    8192, 1);
        GROUP(g0i + 1, 8192, 0,    1);
    }
}

extern "C" void kernel_launch(void* const* d_in, const int* in_sizes, int n_in,
                              void* d_out, int out_size, void* d_ws, size_t ws_size,
                              hipStream_t stream) {
    const float* pe_in  = (const float*)d_in[0];   // [1096, 16384, 2] f32
    const float* params = (const float*)d_in[1];   // [16384, 20] f32
    float* out = (float*)d_out;                    // 2 * 731 * 16384 f32

    tank_kernel<<<NB / 128, 64, 0, stream>>>(pe_in, params, out);
}

// Round 14
// 156.303 us; speedup vs baseline: 1.5123x; 1.5123x over previous
//
#include <hip/hip_runtime.h>
#include <stdint.h>

#define T_TOTAL 1096
#define WARMUP  365
#define NB      16384
#define T_OUT   (T_TOTAL - WARMUP)   // 731
#define U       8                    // steps per group
#define NG      (T_TOTAL / U)        // 137 real groups (+1 dummy)
#define G_STORE 46                   // first group whose prev-group outputs get stored
#define RS      131072u              // input row stride bytes = NB*2*4
#define ORS     65536u               // output row stride bytes = NB*4
#define EOFF    47906816u            // et plane byte offset = T_OUT*NB*4

// Pin a value into a VGPR at this program point (volatile asm chain).
#define KEEP(x) asm volatile("" : "+v"(x))

typedef float f2 __attribute__((ext_vector_type(2)));

// Volatile register-destination global load (saddr form). NOTE (R12 lesson):
// asm-dest loads are only safe at LOW register pressure — the allocator must
// not touch the dest regs between issue and the vmcnt wait. At R11's ~130
// VGPR this held (verified passing). Do not raise pressure in this kernel.
#define GLOAD(dst, off) \
    asm volatile("global_load_dwordx2 %0, %1, %2" \
                 : "=v"(dst) : "v"(off), "s"(pe_in))

// saddr-form store: 32-bit voffset + uniform SGPR base -> no VCC carry adds
// (VCC decongestion was the R11 win).
#define GSTORE(off, val) \
    asm volatile("global_store_dword %0, %1, %2" \
                 :: "v"(off), "v"(val), "s"(out))

// One group of U=8 steps. DO_ET: compute/buffer et (output-only value).
// Stores of the PREVIOUS group's outputs happen at group top, a full group
// after computation; the vmcnt(0) wait therefore never stalls on them.
#define GROUP(g, CUR, NXT, DO_ET) do {                                        \
        asm volatile("s_waitcnt vmcnt(0)" ::: "memory");                      \
        __builtin_amdgcn_sched_barrier(0);                                    \
        {   /* prefetch group g+1 (clamp dummy/overflow to t=0, in-bounds) */ \
            const uint32_t t0n = ((g) + 1 < NG) ? (uint32_t)((g) + 1) * (8u * RS) : 0u; \
            _Pragma("unroll")                                                 \
            for (int k = 0; k < U; ++k) {                                     \
                uint32_t o = boff + t0n + (uint32_t)k * RS;                   \
                GLOAD(NXT[k], o);                                             \
            }                                                                 \
        }                                                                     \
        if ((g) >= G_STORE) {  /* store outputs of group g-1 */               \
            const int tbP = ((g) - 1) * U - WARMUP;                           \
            _Pragma("unroll")                                                 \
            for (int r = 0; r < U; ++r) {                                     \
                int to = tbP + r; if (to < 0) to = 0;   /* scalar clamp */    \
                const uint32_t voq = vb4 + (uint32_t)to * ORS;                \
                GSTORE(voq, oq[r]);                                           \
                GSTORE(voq + EOFF, oe[r]);                                    \
            }                                                                 \
        }                                                                     \
        _Pragma("unroll")                                                     \
        for (int r = 0; r < U; ++r) {                                         \
            const float p  = CUR[r].x;   /* inputs >=0: clip is identity */   \
            const float e  = CUR[r].y;                                        \
            const float ep = kc * e;                                          \
            const float pd = p - ep;                                          \
            const float pe = fmaxf(pd, 0.0f);                                 \
            if (DO_ET) oe[r] = fminf(ep, p + (xp + xf));                      \
            /* u-trick: u = xf - max(-pd,0) = min(xf+pd, xf);                 \
               xf' = max(u,0); xp' = max(xp + min(u,0), 0)  [min(u,0)=-g0] */ \
            const float u  = fminf(xf + pd, xf);                              \
            xf = fmaxf(u, 0.0f);                                              \
            xp = fmaxf(xp + fminf(u, 0.0f), 0.0f);                            \
            const float t1 = k1 * fminf(x2, w1 - xp);                         \
            xp += t1;                                                         \
            x2 = fmaxf(x2 - t1, 0.0f);                                        \
            const float t2 = fmaxf(fmaf(cxs, xs, -(cxp * xp)), 0.0f);         \
            xp += t2;                                                         \
            xs = fmaxf(xs - t2, 0.0f);                                        \
            const float xppe = xp + pe;                                       \
            xf = xf + fmaxf(xppe - w1, 0.0f);                                 \
            xp = fminf(w1, xppe);                                             \
            const float f1v = a0 * xf;                                        \
            const float s1v = fmaf(xf, a1, nh1a1);                            \
            const float s2v = fmaf(xf, a2, nh2a2);                            \
            /* a2>0: h2-select == fmax(s2v,0) */                              \
            const float rsv = fmaxf(s2v, 0.0f) + ((xf > hm) ? s1v : 0.0f);    \
            x2 = x2 + f1v;                                                    \
            xf = fmaxf(xf - (rsv + f1v), 0.0f);                               \
            const float f2v = b0 * x2;                                        \
            const float riv = fmaxf(fmaf(x2, b1, nh3b1), 0.0f);               \
            x2 = fmaxf(x2 - (f2v + riv), 0.0f);                               \
            x3 = x3 + f2v;                                                    \
            const float f3v = c0p * x3;                                       \
            const float rgv = fmaxf(fmaf(x3, c1p, nh4c1), 0.0f);              \
            x3 = fmaxf(x3 - (f3v + rgv), 0.0f);                               \
            x4 = x4 + f3v;                                                    \
            const float rgd = d1 * x4;                                        \
            x4 = fmaxf(x4 - rgd, 0.0f);                                       \
            /* routing: shared numerator N1 = (kk0-dt)*qs + ii + cc0;         \
               q1B = max(N1*dB,0); q1A = max(N1*dA - ccA*dA, 0) — exactly     \
               the reference's ((kk0-dt)qs + ii - rc1 + cc0)/(rk1+dt) */      \
            const bool  c5   = (x5 >= h);                                     \
            const float kk0g = c5 ? gA : gB;                                  \
            const float cc0  = c5 ? ccA : 0.0f;                               \
            const float ii   = (rsv + riv) + (rgv + rgd);                     \
            const float N1   = fmaf(kk0g, qs, ii + cc0);                      \
            const float q1B  = fmaxf(N1 * dB, 0.0f);                          \
            const float q1A  = fmaxf(fmaf(N1, dA, nccAdA), 0.0f);             \
            const bool  cb   = (q1B > he1);                                   \
            const float q1   = cb ? q1A : q1B;                                \
            x5 = cb ? fmaf(kkA, q1A, ccA) : (kkB * q1B);                      \
            qs = q1;                                                          \
            oq[r] = q1;                                                       \
        }                                                                     \
    } while (0)

#define KEEP_CONSTS() do {                                                    \
        KEEP(kc);  KEEP(w1);  KEEP(k1);  KEEP(cxs); KEEP(cxp);                \
        KEEP(a0);  KEEP(b0);  KEEP(c0p); KEEP(hm);                            \
        KEEP(a1);  KEEP(a2);  KEEP(b1);  KEEP(c1p); KEEP(d1);                 \
        KEEP(h);   KEEP(he1);                                                 \
        KEEP(kkA); KEEP(kkB); KEEP(ccA); KEEP(dA);  KEEP(dB);                 \
        KEEP(gA);  KEEP(gB);  KEEP(nccAdA);                                   \
        KEEP(nh1a1); KEEP(nh2a2); KEEP(nh3b1); KEEP(nh4c1);                   \
    } while (0)

// waves_per_eu(1,1): occupancy is structurally 1 wave/EU (256 waves on 1024
// SIMDs); cap removes occupancy pressure -> full VGPR budget, no spills
// (verified R10: VGPR_Count 64 -> 132).
__global__ __attribute__((amdgpu_flat_work_group_size(64, 64)))
__attribute__((amdgpu_waves_per_eu(1, 1)))
void tank_kernel(
    const float* __restrict__ pe_in,   // [T, B, 2]
    const float* __restrict__ params,  // [B, 20]
    float* __restrict__ out)           // q [731,B] then et [731,B]
{
    const int lane = threadIdx.x;          // 0..63, one wave per block
    const int b    = blockIdx.x * 64 + lane;

    float pn[20];
#pragma unroll
    for (int i = 0; i < 20; ++i) pn[i] = params[b * 20 + i];

    float kc  = 0.5f  + pn[0]  * 1.0f;
    float w1  = 1.0f  + pn[1]  * 99.0f;
    float w2  = 1.0f  + pn[2]  * 99.0f;
    float k1  = 0.01f + pn[3]  * 0.99f;
    float k2  = 0.01f + pn[4]  * 0.99f;
    float a0  = 0.01f + pn[5]  * 0.99f;
    float b0  = 0.01f + pn[6]  * 0.99f;
    float c0p = 0.01f + pn[7]  * 0.99f;
    float h1  = pn[8]  * 90.0f;
    float h2  = pn[9]  * 100.0f;
    float a1  = 0.01f + pn[10] * 0.99f;
    float a2  = 0.01f + pn[11] * 0.99f;
    float h3  = pn[12] * 100.0f;
    float b1  = 0.01f + pn[13] * 0.99f;
    float h4  = pn[14] * 100.0f;
    float c1p = 0.01f + pn[15] * 0.99f;
    float d1  = 0.001f+ pn[16] * 0.999f;
    float e1  = 0.01f + pn[17] * 0.99f;
    float e2  = 0.01f + pn[18] * 0.99f;
    float h   = pn[19] * 100.0f;

    const float dt = 0.5f * (1.0f / 1000.0f);
    float invw = 1.0f / (w1 + w2);
    float cxs  = k2 * w1 * invw;
    float cxp  = k2 * w2 * invw;
    float kkA  = 1.0f / (e1 + e2);
    float kkB  = 1.0f / e1;
    float ccA  = e2 * h * kkA;
    float dA   = 1.0f / (kkA + dt);
    float dB   = 1.0f / (kkB + dt);
    float gA   = kkA - dt;
    float gB   = kkB - dt;
    float nh1a1 = -h1 * a1;
    float nh2a2 = -h2 * a2;
    float nh3b1 = -h3 * b1;
    float nh4c1 = -h4 * c1p;
    float hm    = fminf(h1, h2);
    float he1   = h * e1;
    float nccAdA = -ccA * dA;

    float xf = 0.01f, xp = 0.01f, x2 = 0.01f, xs = 0.01f;
    float x3 = 0.01f, x4 = 0.01f, x5 = 0.01f, qs = 0.01f;

    const uint32_t boff = (uint32_t)b * 8u;   // input: lane byte off in a row
    const uint32_t vb4  = (uint32_t)b * 4u;   // output: lane byte off in a row

    f2 bufA[U], bufB[U];
    float oq[U], oe[U];

    // prologue: issue loads for group 0 into set A
#pragma unroll
    for (int k = 0; k < U; ++k) {
        uint32_t o = boff + (uint32_t)k * RS;
        GLOAD(bufA[k], o);
    }

    // Phase 1: pure-warmup groups 0..43 as 22 pairs (no et, no stores).
#pragma clang loop unroll(disable)
    for (int gp = 0; gp < 22; ++gp) {
        KEEP_CONSTS();
        const int g0i = 2 * gp;
        GROUP(g0i,     bufA, bufB, 0);
        GROUP(g0i + 1, bufB, bufA, 0);
    }
    // groups 44 (no et) and 45 (t=360..367: et needed, outputs buffered;
    // stored at top of group 46 with scalar row clamp).
    KEEP_CONSTS();
    GROUP(44, bufA, bufB, 0);
    GROUP(45, bufB, bufA, 1);

    // Phase 2: output groups 46..137 as 46 pairs. Group 137 is a dummy:
    // computes discarded garbage from in-bounds t=0 data; its store slot
    // writes group 136's real outputs (rows 723..730); its prefetch is
    // never waited on.
#pragma clang loop unroll(disable)
    for (int gp = 0; gp < 46; ++gp) {
        KEEP_CONSTS();
        const int g0i = 46 + 2 * gp;
        GROUP(g0i,     bufA, bufB, 1);
        GROUP(g0i + 1, bufB, bufA, 1);
    }
}

extern "C" void kernel_launch(void* const* d_in, const int* in_sizes, int n_in,
                              void* d_out, int out_size, void* d_ws, size_t ws_size,
                              hipStream_t stream) {
    const float* pe_in  = (const float*)d_in[0];   // [1096, 16384, 2] f32
    const float* params = (const float*)d_in[1];   // [16384, 20] f32
    float* out = (float*)d_out;                    // 2 * 731 * 16384 f32

    tank_kernel<<<NB / 64, 64, 0, stream>>>(pe_in, params, out);
}

// Round 15
// 155.551 us; speedup vs baseline: 1.5196x; 1.0048x over previous
//
#include <hip/hip_runtime.h>
#include <stdint.h>

#define T_TOTAL 1096
#define WARMUP  365
#define NB      16384
#define T_OUT   (T_TOTAL - WARMUP)   // 731
#define U       8                    // steps per group
#define NG      (T_TOTAL / U)        // 137 real groups (+1 dummy)
#define G_STORE 46                   // first group whose prev-group outputs get stored
#define RS      131072u              // input row stride bytes = NB*2*4
#define ORS     65536u               // output row stride bytes = NB*4
#define EOFF    47906816u            // et plane byte offset = T_OUT*NB*4

// Pin a value into a VGPR at this program point (volatile asm chain).
#define KEEP(x) asm volatile("" : "+v"(x))

typedef float f2 __attribute__((ext_vector_type(2)));

// Volatile register-destination global load (saddr form). R12 lesson: safe
// only at low register pressure (allocator must not touch dest regs between
// issue and the vmcnt wait). Holds at ~132 VGPR (R11/R14 verified passing).
#define GLOAD(dst, off) \
    asm volatile("global_load_dwordx2 %0, %1, %2" \
                 : "=v"(dst) : "v"(off), "s"(pe_in))

// saddr-form store: 32-bit voffset + uniform SGPR base -> no VCC carry adds.
#define GSTORE(off, val) \
    asm volatile("global_store_dword %0, %1, %2" \
                 :: "v"(off), "v"(val), "s"(out))

// One group of U=8 steps. DO_ET: compute/buffer et (output-only value).
// Stores of the PREVIOUS group's outputs happen at group top, a full group
// after computation; the vmcnt(0) wait therefore never stalls on them.
#define GROUP(g, CUR, NXT, DO_ET) do {                                        \
        asm volatile("s_waitcnt vmcnt(0)" ::: "memory");                      \
        __builtin_amdgcn_sched_barrier(0);                                    \
        {   /* prefetch group g+1 (clamp dummy/overflow to t=0, in-bounds) */ \
            const uint32_t t0n = ((g) + 1 < NG) ? (uint32_t)((g) + 1) * (8u * RS) : 0u; \
            _Pragma("unroll")                                                 \
            for (int k = 0; k < U; ++k) {                                     \
                uint32_t o = boff + t0n + (uint32_t)k * RS;                   \
                GLOAD(NXT[k], o);                                             \
            }                                                                 \
        }                                                                     \
        if ((g) >= G_STORE) {  /* store outputs of group g-1 */               \
            const int tbP = ((g) - 1) * U - WARMUP;                           \
            _Pragma("unroll")                                                 \
            for (int r = 0; r < U; ++r) {                                     \
                int to = tbP + r; if (to < 0) to = 0;   /* scalar clamp */    \
                const uint32_t voq = vb4 + (uint32_t)to * ORS;                \
                GSTORE(voq, oq[r]);                                           \
                GSTORE(voq + EOFF, oe[r]);                                    \
            }                                                                 \
        }                                                                     \
        _Pragma("unroll")                                                     \
        for (int r = 0; r < U; ++r) {                                         \
            const float p  = CUR[r].x;   /* inputs >=0: clip is identity */   \
            const float e  = CUR[r].y;                                        \
            const float pd = fmaf(nkc, e, p);       /* p - kc*e */            \
            const float pe = fmaxf(pd, 0.0f);                                 \
            const float pew1 = pe - w1;             /* off-chain hoist */     \
            if (DO_ET) { const float ep = p - pd;                             \
                         oe[r] = fminf(ep, p + (xp + xf)); }                  \
            /* u-trick: xf' = max(u,0), xp' = max(xp+min(u,0),0) */           \
            const float u  = fminf(xf + pd, xf);                              \
            xf = fmaxf(u, 0.0f);                                              \
            xp = fmaxf(xp + fminf(u, 0.0f), 0.0f);                            \
            const float minv = fminf(x2, w1 - xp);                            \
            const float t1 = k1 * minv;                                       \
            /* t2 decoupled from xp2: cxp*(xp1+t1) distributed */             \
            const float A2 = fmaf(cxs, xs, -(cxp * xp));                      \
            const float B2 = cxpk1 * minv;                                    \
            const float t2 = fmaxf(A2 - B2, 0.0f);                            \
            xp += t1;                                                         \
            x2 = fmaxf(x2 - t1, 0.0f);                                        \
            xp += t2;                                                         \
            xs = fmaxf(xs - t2, 0.0f);                                        \
            const float xppe = xp + pe;                                       \
            xf = xf + fmaxf(xp + pew1, 0.0f);   /* xf1 + max(xppe-w1,0) */    \
            xp = fminf(w1, xppe);                                             \
            const float f1v = a0 * xf;                                        \
            const float s1v = fmaf(xf, a1, nh1a1);                            \
            const float s2v = fmaf(xf, a2, nh2a2);                            \
            /* a2>0: h2-select == fmax(s2v,0) */                              \
            const float rsv = fmaxf(s2v, 0.0f) + ((xf > hm) ? s1v : 0.0f);    \
            x2 = x2 + f1v;                                                    \
            /* fused decay: xf*(1-a0) - rsv, clipped */                       \
            xf = fmaxf(fmaf(na0, xf, xf) - rsv, 0.0f);                        \
            const float f2v = b0 * x2;                                        \
            const float riv = fmaxf(fmaf(x2, b1, nh3b1), 0.0f);               \
            x3 = x3 + f2v;                       /* uses x2b pre-overwrite */ \
            x2 = fmaxf(fmaf(nb0, x2, x2) - riv, 0.0f);                        \
            const float f3v = c0p * x3;                                       \
            const float rgv = fmaxf(fmaf(x3, c1p, nh4c1), 0.0f);              \
            x4 = x4 + f3v;                       /* uses x3a pre-overwrite */ \
            x3 = fmaxf(fmaf(nc0, x3, x3) - rgv, 0.0f);                        \
            const float rgd = d1 * x4;                                        \
            x4 = x4 - rgd;   /* clip redundant: RN(d1*x4)<=x4 for d1<=1 */    \
            const bool  c5   = (x5 >= h);                                     \
            const float kk0g = c5 ? gA : gB;                                  \
            const float cc0  = c5 ? ccA : 0.0f;                               \
            const float ii   = (rsv + riv) + (rgv + rgd);                     \
            const float N1   = fmaf(kk0g, qs, ii + cc0);                      \
            const float q1B  = fmaxf(N1 * dB, 0.0f);                          \
            const float q1A  = fmaxf(fmaf(N1, dA, nccAdA), 0.0f);             \
            const bool  cb   = (q1B > he1);                                   \
            const float q1   = cb ? q1A : q1B;                                \
            x5 = cb ? fmaf(kkA, q1A, ccA) : (kkB * q1B);                      \
            qs = q1;                                                          \
            oq[r] = q1;                                                       \
        }                                                                     \
    } while (0)

#define KEEP_CONSTS() do {                                                    \
        KEEP(nkc); KEEP(w1);  KEEP(k1);  KEEP(cxs); KEEP(cxp); KEEP(cxpk1);   \
        KEEP(a0);  KEEP(na0); KEEP(nb0); KEEP(nc0); KEEP(hm);                 \
        KEEP(a1);  KEEP(a2);  KEEP(b0);  KEEP(b1);  KEEP(c0p); KEEP(c1p);     \
        KEEP(d1);  KEEP(h);   KEEP(he1);                                      \
        KEEP(kkA); KEEP(kkB); KEEP(ccA); KEEP(dA);  KEEP(dB);                 \
        KEEP(gA);  KEEP(gB);  KEEP(nccAdA);                                   \
        KEEP(nh1a1); KEEP(nh2a2); KEEP(nh3b1); KEEP(nh4c1);                   \
    } while (0)

// waves_per_eu(1,1): occupancy is structurally 1 wave/EU (256 waves on 1024
// SIMDs); cap removes occupancy pressure -> full VGPR budget, no spills
// (verified R10: VGPR_Count 64 -> 132).
__global__ __attribute__((amdgpu_flat_work_group_size(64, 64)))
__attribute__((amdgpu_waves_per_eu(1, 1)))
void tank_kernel(
    const float* __restrict__ pe_in,   // [T, B, 2]
    const float* __restrict__ params,  // [B, 20]
    float* __restrict__ out)           // q [731,B] then et [731,B]
{
    const int lane = threadIdx.x;          // 0..63, one wave per block
    const int b    = blockIdx.x * 64 + lane;

    float pn[20];
#pragma unroll
    for (int i = 0; i < 20; ++i) pn[i] = params[b * 20 + i];

    float kc  = 0.5f  + pn[0]  * 1.0f;
    float w1  = 1.0f  + pn[1]  * 99.0f;
    float w2  = 1.0f  + pn[2]  * 99.0f;
    float k1  = 0.01f + pn[3]  * 0.99f;
    float k2  = 0.01f + pn[4]  * 0.99f;
    float a0  = 0.01f + pn[5]  * 0.99f;
    float b0  = 0.01f + pn[6]  * 0.99f;
    float c0p = 0.01f + pn[7]  * 0.99f;
    float h1  = pn[8]  * 90.0f;
    float h2  = pn[9]  * 100.0f;
    float a1  = 0.01f + pn[10] * 0.99f;
    float a2  = 0.01f + pn[11] * 0.99f;
    float h3  = pn[12] * 100.0f;
    float b1  = 0.01f + pn[13] * 0.99f;
    float h4  = pn[14] * 100.0f;
    float c1p = 0.01f + pn[15] * 0.99f;
    float d1  = 0.001f+ pn[16] * 0.999f;
    float e1  = 0.01f + pn[17] * 0.99f;
    float e2  = 0.01f + pn[18] * 0.99f;
    float h   = pn[19] * 100.0f;

    const float dt = 0.5f * (1.0f / 1000.0f);
    float invw = 1.0f / (w1 + w2);
    float cxs  = k2 * w1 * invw;
    float cxp  = k2 * w2 * invw;
    float kkA  = 1.0f / (e1 + e2);
    float kkB  = 1.0f / e1;
    float ccA  = e2 * h * kkA;
    float dA   = 1.0f / (kkA + dt);
    float dB   = 1.0f / (kkB + dt);
    float gA   = kkA - dt;
    float gB   = kkB - dt;
    float nh1a1 = -h1 * a1;
    float nh2a2 = -h2 * a2;
    float nh3b1 = -h3 * b1;
    float nh4c1 = -h4 * c1p;
    float hm    = fminf(h1, h2);
    float he1   = h * e1;
    float nccAdA = -ccA * dA;
    float nkc   = -kc;
    float cxpk1 = cxp * k1;
    float na0   = -a0;
    float nb0   = -b0;
    float nc0   = -c0p;

    float xf = 0.01f, xp = 0.01f, x2 = 0.01f, xs = 0.01f;
    float x3 = 0.01f, x4 = 0.01f, x5 = 0.01f, qs = 0.01f;

    const uint32_t boff = (uint32_t)b * 8u;   // input: lane byte off in a row
    const uint32_t vb4  = (uint32_t)b * 4u;   // output: lane byte off in a row

    f2 bufA[U], bufB[U];
    float oq[U], oe[U];

    // prologue: issue loads for group 0 into set A
#pragma unroll
    for (int k = 0; k < U; ++k) {
        uint32_t o = boff + (uint32_t)k * RS;
        GLOAD(bufA[k], o);
    }

    // Phase 1: pure-warmup groups 0..43 as 22 pairs (no et, no stores).
#pragma clang loop unroll(disable)
    for (int gp = 0; gp < 22; ++gp) {
        KEEP_CONSTS();
        const int g0i = 2 * gp;
        GROUP(g0i,     bufA, bufB, 0);
        GROUP(g0i + 1, bufB, bufA, 0);
    }
    // groups 44 (no et) and 45 (t=360..367: et needed, outputs buffered;
    // stored at top of group 46 with scalar row clamp).
    KEEP_CONSTS();
    GROUP(44, bufA, bufB, 0);
    GROUP(45, bufB, bufA, 1);

    // Phase 2: output groups 46..137 as 46 pairs. Group 137 is a dummy:
    // computes discarded garbage from in-bounds t=0 data; its store slot
    // writes group 136's real outputs (rows 723..730); its prefetch is
    // never waited on.
#pragma clang loop unroll(disable)
    for (int gp = 0; gp < 46; ++gp) {
        KEEP_CONSTS();
        const int g0i = 46 + 2 * gp;
        GROUP(g0i,     bufA, bufB, 1);
        GROUP(g0i + 1, bufB, bufA, 1);
    }
}

extern "C" void kernel_launch(void* const* d_in, const int* in_sizes, int n_in,
                              void* d_out, int out_size, void* d_ws, size_t ws_size,
                              hipStream_t stream) {
    const float* pe_in  = (const float*)d_in[0];   // [1096, 16384, 2] f32
    const float* params = (const float*)d_in[1];   // [16384, 20] f32
    float* out = (float*)d_out;                    // 2 * 731 * 16384 f32

    tank_kernel<<<NB / 64, 64, 0, stream>>>(pe_in, params, out);
}

// Round 16
// 149.602 us; speedup vs baseline: 1.5800x; 1.0398x over previous
//
#include <hip/hip_runtime.h>
#include <stdint.h>

#define T_TOTAL 1096
#define WARMUP  365
#define NB      16384
#define T_OUT   (T_TOTAL - WARMUP)   // 731
#define U       8                    // steps per group
#define NG      (T_TOTAL / U)        // 137 real groups (+1 dummy)
#define RS      131072u              // input row stride bytes = NB*2*4
#define ORS     65536u               // output row stride bytes = NB*4

// Pin a value into a VGPR at this program point (volatile asm chain).
#define KEEP(x) asm volatile("" : "+v"(x))

typedef float f2 __attribute__((ext_vector_type(2)));

// Volatile register-destination global load (saddr form). R12 lesson: safe
// only at low register pressure. Holds at ~132 VGPR (R11/R14/R15 passing).
#define GLOAD(dst, off) \
    asm volatile("global_load_dwordx2 %0, %1, %2" \
                 : "=v"(dst) : "v"(off), "s"(pe_in))

// saddr-form stores: 32-bit voffset + uniform SGPR base (no VCC carry adds).
// Separate bases for the q plane and the et plane (kills +EOFF adds).
#define GSTORE_Q(off, val) \
    asm volatile("global_store_dword %0, %1, %2" \
                 :: "v"(off), "v"(val), "s"(out))
#define GSTORE_E(off, val) \
    asm volatile("global_store_dword %0, %1, %2" \
                 :: "v"(off), "v"(val), "s"(oute))

// ---- compute body for one group of U=8 steps (shared by all variants) ----
#define BODY8(CUR, DO_ET)                                                      \
        _Pragma("unroll")                                                      \
        for (int r = 0; r < U; ++r) {                                          \
            const float p  = CUR[r].x;   /* inputs >=0: clip is identity */    \
            const float e  = CUR[r].y;                                         \
            const float pd = fmaf(nkc, e, p);       /* p - kc*e */             \
            const float pe = fmaxf(pd, 0.0f);                                  \
            const float pew1 = pe - w1;             /* off-chain hoist */      \
            if (DO_ET) { const float ep = p - pd;                              \
                         oe[r] = fminf(ep, p + (xp + xf)); }                   \
            /* u-trick: xf' = max(u,0), xp' = max(xp+min(u,0),0) */            \
            const float u  = fminf(xf + pd, xf);                               \
            xf = fmaxf(u, 0.0f);                                               \
            xp = fmaxf(xp + fminf(u, 0.0f), 0.0f);                             \
            const float minv = fminf(x2, w1 - xp);                             \
            const float t1 = k1 * minv;                                        \
            /* t2 decoupled from xp2: cxp*(xp1+t1) distributed */              \
            const float A2 = fmaf(cxs, xs, -(cxp * xp));                       \
            const float B2 = cxpk1 * minv;                                     \
            const float t2 = fmaxf(A2 - B2, 0.0f);                             \
            xp += t1;                                                          \
            x2 = x2 - t1;    /* clip exact-redundant: t1<=minv<=x2 (RN) */     \
            xp += t2;                                                          \
            xs = xs - t2;    /* clip exact-redundant: t2<=RN(cxs*xs)<=xs */    \
            const float xppe = xp + pe;                                        \
            xf = xf + fmaxf(xp + pew1, 0.0f);   /* xf1 + max(xppe-w1,0) */     \
            xp = fminf(w1, xppe);                                              \
            const float f1v = a0 * xf;                                         \
            const float s1v = fmaf(xf, a1, nh1a1);                             \
            const float s2v = fmaf(xf, a2, nh2a2);                             \
            /* a2>0: h2-select == fmax(s2v,0) */                               \
            const float rsv = fmaxf(s2v, 0.0f) + ((xf > hm) ? s1v : 0.0f);     \
            x2 = x2 + f1v;                                                     \
            xf = fmaxf(fmaf(na0, xf, xf) - rsv, 0.0f);                         \
            const float f2v = b0 * x2;                                         \
            const float riv = fmaxf(fmaf(x2, b1, nh3b1), 0.0f);                \
            x3 = x3 + f2v;                       /* uses x2 pre-overwrite */   \
            x2 = fmaxf(fmaf(nb0, x2, x2) - riv, 0.0f);                         \
            const float f3v = c0p * x3;                                        \
            const float rgv = fmaxf(fmaf(x3, c1p, nh4c1), 0.0f);               \
            x4 = x4 + f3v;                       /* uses x3 pre-overwrite */   \
            x3 = fmaxf(fmaf(nc0, x3, x3) - rgv, 0.0f);                         \
            const float rgd = d1 * x4;                                         \
            x4 = x4 - rgd;   /* clip redundant: RN(d1*x4)<=x4 for d1<=1 */     \
            const bool  c5   = (x5 >= h);                                      \
            const float kk0g = c5 ? gA : gB;                                   \
            const float cc0  = c5 ? ccA : 0.0f;                                \
            const float ii   = (rsv + riv) + (rgv + rgd);                      \
            const float N1   = fmaf(kk0g, qs, ii + cc0);                       \
            const float q1B  = fmaxf(N1 * dB, 0.0f);                           \
            const float q1A  = fmaxf(fmaf(N1, dA, nccAdA), 0.0f);              \
            const bool  cb   = (q1B > he1);                                    \
            const float q1   = cb ? q1A : q1B;                                 \
            x5 = cb ? fmaf(kkA, q1A, ccA) : (kkB * q1B);                       \
            qs = q1;                                                           \
            oq[r] = q1;                                                        \
        }

#define PREFETCH(g, NXT) do {                                                  \
        const uint32_t t0n = ((g) + 1 < NG) ? (uint32_t)((g) + 1) * (8u * RS) : 0u; \
        _Pragma("unroll")                                                      \
        for (int k = 0; k < U; ++k) {                                          \
            uint32_t o = boff + t0n + (uint32_t)k * RS;                        \
            GLOAD(NXT[k], o);                                                  \
        }                                                                      \
    } while (0)

#define WAIT() do {                                                            \
        asm volatile("s_waitcnt vmcnt(0)" ::: "memory");                       \
        __builtin_amdgcn_sched_barrier(0);                                     \
    } while (0)

// no-store group (warmup)
#define GROUP_NS(g, CUR, NXT, DO_ET) do {                                      \
        WAIT(); PREFETCH(g, NXT); BODY8(CUR, DO_ET)                            \
    } while (0)

// clamp-store group (g=46 only: stores group 45's outputs, rows clamp to 0;
// row 0 garbage is overwritten later in program order by the genuine t=365)
#define GROUP_CL(g, CUR, NXT) do {                                             \
        WAIT(); PREFETCH(g, NXT);                                              \
        {                                                                      \
            const int tbP = ((g) - 1) * U - WARMUP;                            \
            _Pragma("unroll")                                                  \
            for (int r = 0; r < U; ++r) {                                      \
                int to = tbP + r; if (to < 0) to = 0;                          \
                const uint32_t v = vb4 + (uint32_t)to * ORS;                   \
                GSTORE_Q(v, oq[r]); GSTORE_E(v, oe[r]);                        \
            }                                                                  \
        }                                                                      \
        BODY8(CUR, 1)                                                          \
    } while (0)

// running-voq store group (phase-2 hot path): output rows are globally
// contiguous across groups -> one v_add per step for addressing.
#define GROUP_RV(g, CUR, NXT) do {                                             \
        WAIT(); PREFETCH(g, NXT);                                              \
        _Pragma("unroll")                                                      \
        for (int r = 0; r < U; ++r) {                                          \
            GSTORE_Q(voq, oq[r]); GSTORE_E(voq, oe[r]);                        \
            voq += ORS;                                                        \
        }                                                                      \
        BODY8(CUR, 1)                                                          \
    } while (0)

#define KEEP_CONSTS() do {                                                     \
        KEEP(nkc); KEEP(w1);  KEEP(k1);  KEEP(cxs); KEEP(cxp); KEEP(cxpk1);    \
        KEEP(a0);  KEEP(na0); KEEP(nb0); KEEP(nc0); KEEP(hm);                  \
        KEEP(a1);  KEEP(a2);  KEEP(b0);  KEEP(b1);  KEEP(c0p); KEEP(c1p);      \
        KEEP(d1);  KEEP(h);   KEEP(he1);                                       \
        KEEP(kkA); KEEP(kkB); KEEP(ccA); KEEP(dA);  KEEP(dB);                  \
        KEEP(gA);  KEEP(gB);  KEEP(nccAdA);                                    \
        KEEP(nh1a1); KEEP(nh2a2); KEEP(nh3b1); KEEP(nh4c1);                    \
    } while (0)

// waves_per_eu(1,1): occupancy is structurally 1 wave/EU (256 waves on 1024
// SIMDs); cap removes occupancy pressure -> full VGPR budget, no spills
// (verified R10: VGPR_Count 64 -> 132).
__global__ __attribute__((amdgpu_flat_work_group_size(64, 64)))
__attribute__((amdgpu_waves_per_eu(1, 1)))
void tank_kernel(
    const float* __restrict__ pe_in,   // [T, B, 2]
    const float* __restrict__ params,  // [B, 20]
    float* __restrict__ out)           // q [731,B] then et [731,B]
{
    const int lane = threadIdx.x;          // 0..63, one wave per block
    const int b    = blockIdx.x * 64 + lane;

    const float* oute = out + (size_t)T_OUT * NB;   // et plane SGPR base

    float pn[20];
#pragma unroll
    for (int i = 0; i < 20; ++i) pn[i] = params[b * 20 + i];

    float kc  = 0.5f  + pn[0]  * 1.0f;
    float w1  = 1.0f  + pn[1]  * 99.0f;
    float w2  = 1.0f  + pn[2]  * 99.0f;
    float k1  = 0.01f + pn[3]  * 0.99f;
    float k2  = 0.01f + pn[4]  * 0.99f;
    float a0  = 0.01f + pn[5]  * 0.99f;
    float b0  = 0.01f + pn[6]  * 0.99f;
    float c0p = 0.01f + pn[7]  * 0.99f;
    float h1  = pn[8]  * 90.0f;
    float h2  = pn[9]  * 100.0f;
    float a1  = 0.01f + pn[10] * 0.99f;
    float a2  = 0.01f + pn[11] * 0.99f;
    float h3  = pn[12] * 100.0f;
    float b1  = 0.01f + pn[13] * 0.99f;
    float h4  = pn[14] * 100.0f;
    float c1p = 0.01f + pn[15] * 0.99f;
    float d1  = 0.001f+ pn[16] * 0.999f;
    float e1  = 0.01f + pn[17] * 0.99f;
    float e2  = 0.01f + pn[18] * 0.99f;
    float h   = pn[19] * 100.0f;

    const float dt = 0.5f * (1.0f / 1000.0f);
    float invw = 1.0f / (w1 + w2);
    float cxs  = k2 * w1 * invw;
    float cxp  = k2 * w2 * invw;
    float kkA  = 1.0f / (e1 + e2);
    float kkB  = 1.0f / e1;
    float ccA  = e2 * h * kkA;
    float dA   = 1.0f / (kkA + dt);
    float dB   = 1.0f / (kkB + dt);
    float gA   = kkA - dt;
    float gB   = kkB - dt;
    float nh1a1 = -h1 * a1;
    float nh2a2 = -h2 * a2;
    float nh3b1 = -h3 * b1;
    float nh4c1 = -h4 * c1p;
    float hm    = fminf(h1, h2);
    float he1   = h * e1;
    float nccAdA = -ccA * dA;
    float nkc   = -kc;
    float cxpk1 = cxp * k1;
    float na0   = -a0;
    float nb0   = -b0;
    float nc0   = -c0p;

    float xf = 0.01f, xp = 0.01f, x2 = 0.01f, xs = 0.01f;
    float x3 = 0.01f, x4 = 0.01f, x5 = 0.01f, qs = 0.01f;

    const uint32_t boff = (uint32_t)b * 8u;   // input: lane byte off in a row
    const uint32_t vb4  = (uint32_t)b * 4u;   // output: lane byte off in a row

    f2 bufA[U], bufB[U];
    float oq[U], oe[U];

    // prologue: issue loads for group 0 into set A
#pragma unroll
    for (int k = 0; k < U; ++k) {
        uint32_t o = boff + (uint32_t)k * RS;
        GLOAD(bufA[k], o);
    }

    // Phase 1: pure-warmup groups 0..43 as 22 pairs (no et, no stores).
#pragma clang loop unroll(disable)
    for (int gp = 0; gp < 22; ++gp) {
        KEEP_CONSTS();
        const int g0i = 2 * gp;
        GROUP_NS(g0i,     bufA, bufB, 0);
        GROUP_NS(g0i + 1, bufB, bufA, 0);
    }
    // group 44 (no et); group 45 (t=360..367: et computed, outputs buffered).
    KEEP_CONSTS();
    GROUP_NS(44, bufA, bufB, 0);
    GROUP_NS(45, bufB, bufA, 1);

    // group 46: stores group 45's outputs with row clamp (outside hot loop).
    KEEP_CONSTS();
    GROUP_CL(46, bufA, bufB);

    // running output address: group 47 stores group 46's outputs, rows 3..10,
    // and rows are globally contiguous from here on.
    uint32_t voq = vb4 + 3u * ORS;
    GROUP_RV(47, bufB, bufA);

    // Phase 2: groups 48..137 as 45 pairs. Group 137 is a dummy: computes
    // discarded garbage from in-bounds t=0 data; its store slot writes group
    // 136's real outputs (rows 723..730); its prefetch is never waited on.
#pragma clang loop unroll(disable)
    for (int gp = 0; gp < 45; ++gp) {
        KEEP_CONSTS();
        const int g0i = 48 + 2 * gp;
        GROUP_RV(g0i,     bufA, bufB);
        GROUP_RV(g0i + 1, bufB, bufA);
    }
}

extern "C" void kernel_launch(void* const* d_in, const int* in_sizes, int n_in,
                              void* d_out, int out_size, void* d_ws, size_t ws_size,
                              hipStream_t stream) {
    const float* pe_in  = (const float*)d_in[0];   // [1096, 16384, 2] f32
    const float* params = (const float*)d_in[1];   // [16384, 20] f32
    float* out = (float*)d_out;                    // 2 * 731 * 16384 f32

    tank_kernel<<<NB / 64, 64, 0, stream>>>(pe_in, params, out);
}